// Round 4
// baseline (457.752 us; speedup 1.0000x reference)
//
#include <hip/hip_runtime.h>

typedef unsigned short us;
typedef short s16x8 __attribute__((ext_vector_type(8)));
typedef float f32x4 __attribute__((ext_vector_type(4)));

__device__ __forceinline__ us f2bf(float f) {
  union { float f; unsigned u; } v; v.f = f;
  unsigned u = v.u;
  u += 0x7fffu + ((u >> 16) & 1u);   // RNE
  return (us)(u >> 16);
}
__device__ __forceinline__ float bf2f(us u) {
  union { unsigned u; float f; } v; v.u = ((unsigned)u) << 16; return v.f;
}
__device__ __forceinline__ s16x8 ld8(const us* p) { return *(const s16x8*)p; }

#define MFMA(a, b, c) __builtin_amdgcn_mfma_f32_16x16x32_bf16(a, b, c, 0, 0, 0)

// wave-local LDS fence: drain this wave's LDS ops; no cross-wave barrier.
__device__ __forceinline__ void lds_fence() {
  asm volatile("s_waitcnt lgkmcnt(0)" ::: "memory");
}

__device__ __forceinline__ float qsum(float v) {
  v += __shfl_xor(v, 1, 64); v += __shfl_xor(v, 2, 64);
  v += __shfl_xor(v, 4, 64); v += __shfl_xor(v, 8, 64);
  return v;
}

// fast exact-erf GELU: A&S 7.1.26, |err(erf)| <= 1.5e-7
__device__ __forceinline__ float gelu_fast(float x) {
  float ax = fabsf(x);
  float t = __builtin_amdgcn_rcpf(1.f + 0.3275911f * ax);
  float p = t * (0.254829592f +
            t * (-0.284496736f +
            t * (1.421413741f +
            t * (-1.453152027f +
            t * 1.061405429f))));
  float e = __expf(-ax * ax);
  float er = copysignf(1.f - p * e, x);
  return 0.5f * x * (1.f + er);
}

// ---------- prep: weight swizzles + combined rpb+mask tables.
// B-swizzle: dst[((k>>3)*N + n)*8 + (k&7)] = bf16(W[n][k]) -> B-frag = one 16B load.
// rpbm[h][cls][n1][n2] = bf16(rpb + mask), cls = (wh==15)*2 + (ww==15).
__global__ void prep_kernel(const float* __restrict__ qkv_w, const float* __restrict__ proj_w,
                            const float* __restrict__ fc1_w, const float* __restrict__ fc2_w,
                            const float* __restrict__ rpb_table,
                            us* __restrict__ qkvw, us* __restrict__ projw,
                            us* __restrict__ fc1w, us* __restrict__ fc2w,
                            us* __restrict__ rpbm) {
  int id = blockIdx.x * 256 + threadIdx.x;
  if (id < 49152) {  // qkv (384,128); fold q-scale into Q cols (n<128)
    int n = id % 384, k = id / 384;
    float v = qkv_w[n * 128 + k];
    if (n < 128) v *= 0.17677669529663687f;
    qkvw[(((k >> 3) * 384 + n) << 3) + (k & 7)] = f2bf(v);
    return;
  }
  id -= 49152;
  if (id < 16384) { int n = id % 128, k = id / 128;
    projw[(((k >> 3) * 128 + n) << 3) + (k & 7)] = f2bf(proj_w[n * 128 + k]); return; }
  id -= 16384;
  if (id < 65536) { int n = id % 512, k = id / 512;
    fc1w[(((k >> 3) * 512 + n) << 3) + (k & 7)] = f2bf(fc1_w[n * 128 + k]); return; }
  id -= 65536;
  if (id < 65536) { int n = id % 128, k = id / 128;
    fc2w[(((k >> 3) * 128 + n) << 3) + (k & 7)] = f2bf(fc2_w[n * 512 + k]); return; }
  id -= 65536;
  {
    int h = id >> 14, cls = (id >> 12) & 3, e = id & 4095;
    int n1 = e >> 6, n2 = e & 63;
    int r1 = n1 >> 3, c1 = n1 & 7, r2 = n2 >> 3, c2 = n2 & 7;
    int cH = cls >> 1, cW = cls & 1;
    int cq = (cH ? (r1 < 4 ? 1 : 2) : 0) * 3 + (cW ? (c1 < 4 ? 1 : 2) : 0);
    int ck = (cH ? (r2 < 4 ? 1 : 2) : 0) * 3 + (cW ? (c2 < 4 ? 1 : 2) : 0);
    int ridx = (r1 - r2 + 7) * 15 + (c1 - c2 + 7);
    float v = rpb_table[ridx * 4 + h] + (cq != ck ? -100.f : 0.f);
    rpbm[id] = f2bf(v);
  }
}

// ---------- K1: fused per-window QKV GEMM + attention, 16 waves (1024 thr).
// Wave w: head (w>>2), row-quarter (w&3). GEMM: 32 rows x {Q,K,V} head slice
// (acc[2][6] = 48 acc regs). Attention: 2 q-tiles per wave.
// LDS: A[128][136] (aliases Qs, later aliases per-wave P buffers) | Ks | Vts
// = 104448 B -> 1 block/CU, but 16 waves = 4 waves/SIMD (vs 2 before).
// P transpose buffers live in the dead Qs region after aq preload (+1 barrier).
__global__ __launch_bounds__(1024) void qkv_attn_kernel(
    const float* __restrict__ x_v, const us* __restrict__ qkvw,
    const float* __restrict__ qkv_b, const us* __restrict__ rpbm,
    us* __restrict__ attn_out) {
  __shared__ __align__(16) unsigned char smem[104448];
  us* A   = (us*)smem;               // [128][136] bf16 rolled-x staging
  us* Qs  = (us*)smem;               // [128][136] tok-major (aliases A)
  us* Ks  = (us*)(smem + 34816);     // [128][136] tok-major
  us* Vts = (us*)(smem + 69632);     // [128][136] d-major (V transposed)

  int w = blockIdx.x;
  int b = w >> 8, wi = w & 255, wh = wi >> 4, ww = wi & 15;
  int tid = threadIdx.x;

  { // gather: rolled(p) = orig((p+4)&127); 1024 threads, 16 floats each
    int token = tid >> 3, oct = tid & 7;
    int t = token >> 6, n = token & 63, rr = n >> 3, cc = n & 7;
    int hs = (wh * 8 + rr + 4) & 127, wsc = (ww * 8 + cc + 4) & 127;
    const float* src = x_v + (size_t)((b * 2 + t) * 16384 + hs * 128 + wsc) * 128 + oct * 16;
    us* dst = A + token * 136 + oct * 16;
#pragma unroll
    for (int i = 0; i < 2; ++i) {
      float4 f0 = ((const float4*)src)[2 * i];
      float4 f1 = ((const float4*)src)[2 * i + 1];
      s16x8 v;
      v[0] = (short)f2bf(f0.x); v[1] = (short)f2bf(f0.y);
      v[2] = (short)f2bf(f0.z); v[3] = (short)f2bf(f0.w);
      v[4] = (short)f2bf(f1.x); v[5] = (short)f2bf(f1.y);
      v[6] = (short)f2bf(f1.z); v[7] = (short)f2bf(f1.w);
      *(s16x8*)(dst + i * 8) = v;
    }
  }
  __syncthreads();

  int lane = tid & 63, wv = tid >> 6, quad = lane >> 4, c16 = lane & 15;
  int h = wv >> 2, rq = wv & 3;
  int clsid = ((wh == 15) ? 2 : 0) + ((ww == 15) ? 1 : 0);
  int cb = h * 32;  // column base of this head

  // ---- QKV GEMM: wave -> head h, rows rq*32..rq*32+31.
  int rb = rq * 32;
  f32x4 acc[2][6];
#pragma unroll
  for (int mi = 0; mi < 2; ++mi)
#pragma unroll
    for (int ni = 0; ni < 6; ++ni) acc[mi][ni] = (f32x4){0.f, 0.f, 0.f, 0.f};
#pragma unroll
  for (int ks = 0; ks < 4; ++ks) {
    int k0 = ks * 32;
    s16x8 af[2];
#pragma unroll
    for (int mi = 0; mi < 2; ++mi)
      af[mi] = ld8(A + (rb + mi * 16 + c16) * 136 + k0 + quad * 8);
#pragma unroll
    for (int ni = 0; ni < 6; ++ni) {
      int gcol = (ni >> 1) * 128 + cb + (ni & 1) * 16 + c16;
      s16x8 bf = ld8(qkvw + ((((k0 >> 3) + quad) * 384 + gcol) << 3));
#pragma unroll
      for (int mi = 0; mi < 2; ++mi) acc[mi][ni] = MFMA(af[mi], bf, acc[mi][ni]);
    }
  }
  // all waves done READING A before Q writes overwrite the aliased bytes
  __syncthreads();
#pragma unroll
  for (int ni = 0; ni < 6; ++ni) {
    int part = ni >> 1, colh = (ni & 1) * 16 + c16;
    int col = cb + colh;
    float bias = qkv_b[part * 128 + col];
    if (part == 0) bias *= 0.17677669529663687f;
#pragma unroll
    for (int mi = 0; mi < 2; ++mi)
#pragma unroll
      for (int r = 0; r < 4; ++r) {
        int tok = rb + mi * 16 + quad * 4 + r;
        us v = f2bf(acc[mi][ni][r] + bias);
        if (part == 0) Qs[tok * 136 + col] = v;          // tok-major
        else if (part == 1) Ks[tok * 136 + col] = v;     // tok-major
        else Vts[col * 136 + tok] = v;                   // d-major
      }
  }
  __syncthreads();  // all waves' Q/K/V visible

  // ---- preload this wave's 2 Q-frags, then Qs region becomes P buffers.
  s16x8 aq[2];
#pragma unroll
  for (int qq = 0; qq < 2; ++qq)
    aq[qq] = ld8(Qs + (((rq * 2 + qq) * 16) + c16) * 136 + cb + quad * 8);
  __syncthreads();  // Qs reads done everywhere; region reusable

  us* Pw = (us*)smem + wv * 1088;  // per-wave [16][68] (2176 B, in old Qs/A)
  const us* rsrc = rpbm + ((h * 4 + clsid) << 12);

#pragma unroll
  for (int qq = 0; qq < 2; ++qq) {
    int q0 = (rq * 2 + qq) * 16;
    // rpb+mask: 16 scalar 2B loads (period-64 table; nj and nj^4 identical)
    us rb16[4][4];
#pragma unroll
    for (int nj = 0; nj < 4; ++nj) {
      int nk = (nj * 16 + c16) & 63;
#pragma unroll
      for (int r = 0; r < 4; ++r) {
        int nq = (q0 + quad * 4 + r) & 63;
        rb16[nj][r] = rsrc[nq * 64 + nk];
      }
    }
    f32x4 sacc[8];
#pragma unroll
    for (int nj = 0; nj < 8; ++nj) {
      s16x8 bk = ld8(Ks + (nj * 16 + c16) * 136 + cb + quad * 8);
      f32x4 z = (f32x4){0.f, 0.f, 0.f, 0.f};
      sacc[nj] = MFMA(aq[qq], bk, z);
    }
    // softmax without max-subtraction (|scores| << 80, masked = -100 -> exp ~ 0)
    float sm[4] = {0.f, 0.f, 0.f, 0.f};
#pragma unroll
    for (int nj = 0; nj < 8; ++nj)
#pragma unroll
      for (int r = 0; r < 4; ++r) {
        float pp = __expf(sacc[nj][r] + bf2f(rb16[nj & 3][r]));
        sacc[nj][r] = pp;
        sm[r] += pp;
      }
    float inv[4];
#pragma unroll
    for (int r = 0; r < 4; ++r) inv[r] = 1.f / qsum(sm[r]);

    // PV in two k-halves through the small per-wave P buffer
    f32x4 oacc[2];
    oacc[0] = (f32x4){0.f, 0.f, 0.f, 0.f};
    oacc[1] = (f32x4){0.f, 0.f, 0.f, 0.f};
#pragma unroll
    for (int kh = 0; kh < 2; ++kh) {
#pragma unroll
      for (int njl = 0; njl < 4; ++njl)
#pragma unroll
        for (int r = 0; r < 4; ++r)
          Pw[(quad * 4 + r) * 68 + njl * 16 + c16] =
              f2bf(sacc[kh * 4 + njl][r] * inv[r]);
      lds_fence();
#pragma unroll
      for (int ksl = 0; ksl < 2; ++ksl) {
        s16x8 ap = ld8(Pw + c16 * 68 + ksl * 32 + quad * 8);
#pragma unroll
        for (int nt = 0; nt < 2; ++nt) {
          s16x8 bv = ld8(Vts + (cb + nt * 16 + c16) * 136 + kh * 64 + ksl * 32 + quad * 8);
          oacc[nt] = MFMA(ap, bv, oacc[nt]);
        }
      }
      lds_fence();  // Pw WAR before next half / next q-tile
    }
#pragma unroll
    for (int nt = 0; nt < 2; ++nt)
#pragma unroll
      for (int r = 0; r < 4; ++r) {
        int tok = q0 + quad * 4 + r;
        attn_out[((size_t)w * 128 + tok) * 128 + cb + nt * 16 + c16] =
            f2bf(oacc[nt][r]);
      }
  }
}

// ---------- K3: fused proj+LN2+MLP+LN1; 64 tokens/block (2048 blocks), wave owns
// 16 rows. Accumulator live-range merged: proj C-init = x_v + proj_b (xv array
// gone); MLP o C-init = y (y dies at MLP start); f C-init = fc1_b.
// Peak acc ~48 (was ~96) -> target 3-4 waves/SIMD.
__global__ __launch_bounds__(256) void fused_kernel5(
    const us* __restrict__ attn_ws, const us* __restrict__ projw,
    const float* __restrict__ proj_b, const float* __restrict__ x_v,
    const us* __restrict__ fc1w, const us* __restrict__ fc2w,
    const float* __restrict__ fc1_b, const float* __restrict__ fc2_b,
    const float* __restrict__ n2w, const float* __restrict__ n2b,
    const float* __restrict__ n1w, const float* __restrict__ n1b,
    float* __restrict__ out) {
  __shared__ __align__(16) unsigned char smem[26624];
  us* A = (us*)smem;  // [64][136] attn tile -> LN2'd x (each wave: own 16 rows)
  int blk = blockIdx.x;
  int w = blk >> 1, hb = (blk & 1) * 64;
  int b = w >> 8, wi = w & 255, wh = wi >> 4, ww = wi & 15;
  int tid = threadIdx.x;
  int lane = tid & 63, wv = tid >> 6, quad = lane >> 4, c16 = lane & 15;
  int r0 = wv * 16;  // local row base within A
  us* Hw = (us*)(smem + 17408 + wv * 2304);  // per-wave [16][72] gelu chunk

  {  // wave stages its own 16 rows (lane -> row r0+(lane>>2), 32 cols)
    int lr = r0 + (lane >> 2), q = lane & 3;
    const us* src = attn_ws + ((size_t)w * 128 + hb + lr) * 128 + q * 32;
    us* dst = A + lr * 136 + q * 32;
#pragma unroll
    for (int i = 0; i < 4; ++i) *(s16x8*)(dst + i * 8) = ld8(src + i * 8);
  }

  // residual addresses; seed proj accumulator with x_v + proj_b directly
  size_t grow[4];
#pragma unroll
  for (int r = 0; r < 4; ++r) {
    int tt = hb + r0 + quad * 4 + r;
    int t = tt >> 6, n = tt & 63, rr = n >> 3, cc2 = n & 7;
    int hf = (wh * 8 + rr + 4) & 127, wf = (ww * 8 + cc2 + 4) & 127;
    grow[r] = (size_t)((b * 2 + t) * 16384 + hf * 128 + wf) * 128;
  }
  f32x4 y[8];
#pragma unroll
  for (int ni = 0; ni < 8; ++ni) {
    float pb = proj_b[ni * 16 + c16];
#pragma unroll
    for (int r = 0; r < 4; ++r) y[ni][r] = x_v[grow[r] + ni * 16 + c16] + pb;
  }
  lds_fence();  // staging visible to own wave

  // ---- proj: 16 rows x 128 cols, K=128; accumulates onto residual seed
#pragma unroll
  for (int ks = 0; ks < 4; ++ks) {
    int k0 = ks * 32;
    s16x8 af = ld8(A + (r0 + c16) * 136 + k0 + quad * 8);
#pragma unroll
    for (int ni = 0; ni < 8; ++ni) {
      s16x8 bf = ld8(projw + ((((k0 >> 3) + quad) * 128 + ni * 16 + c16) << 3));
      y[ni] = MFMA(af, bf, y[ni]);
    }
  }

  // ---- LN2 (wave-local); LN2'd x -> A
  {
    float sum[4] = {0.f, 0.f, 0.f, 0.f}, sq[4] = {0.f, 0.f, 0.f, 0.f};
#pragma unroll
    for (int ni = 0; ni < 8; ++ni)
#pragma unroll
      for (int r = 0; r < 4; ++r) {
        float v = y[ni][r];
        sum[r] += v; sq[r] += v * v;
      }
#pragma unroll
    for (int r = 0; r < 4; ++r) {
      float s = qsum(sum[r]), q = qsum(sq[r]);
      float mean = s * 0.0078125f;
      float rstd = rsqrtf(q * 0.0078125f - mean * mean + 1e-5f);
      int m = r0 + quad * 4 + r;
#pragma unroll
      for (int ni = 0; ni < 8; ++ni) {
        int col = ni * 16 + c16;
        A[m * 136 + col] = f2bf((y[ni][r] - mean) * rstd * n2w[col] + n2b[col]);
      }
    }
  }
  lds_fence();

  // ---- MLP: o seeded with y (z = y + fc2(...) via MFMA C-chaining); y dies.
  f32x4 o[8];
#pragma unroll
  for (int ni = 0; ni < 8; ++ni) o[ni] = y[ni];

#pragma unroll
  for (int cc = 0; cc < 8; ++cc) {
    f32x4 f[4];
#pragma unroll
    for (int ni = 0; ni < 4; ++ni) {
      float bb = fc1_b[cc * 64 + ni * 16 + c16];
      f[ni] = (f32x4){bb, bb, bb, bb};
    }
#pragma unroll
    for (int ks = 0; ks < 4; ++ks) {
      int k0 = ks * 32;
      s16x8 af = ld8(A + (r0 + c16) * 136 + k0 + quad * 8);
#pragma unroll
      for (int ni = 0; ni < 4; ++ni) {
        s16x8 bf = ld8(fc1w + ((((k0 >> 3) + quad) * 512 + cc * 64 + ni * 16 + c16) << 3));
        f[ni] = MFMA(af, bf, f[ni]);
      }
    }
#pragma unroll
    for (int ni = 0; ni < 4; ++ni)
#pragma unroll
      for (int r = 0; r < 4; ++r)
        Hw[(quad * 4 + r) * 72 + ni * 16 + c16] = f2bf(gelu_fast(f[ni][r]));
    lds_fence();
#pragma unroll
    for (int ks2 = 0; ks2 < 2; ++ks2) {
      s16x8 ah = ld8(Hw + c16 * 72 + ks2 * 32 + quad * 8);
#pragma unroll
      for (int ni = 0; ni < 8; ++ni) {
        s16x8 bf = ld8(fc2w + (((cc * 8 + ks2 * 4 + quad) * 128 + ni * 16 + c16) << 3));
        o[ni] = MFMA(ah, bf, o[ni]);
      }
    }
    lds_fence();  // Hw WAR before next chunk
  }

  // ---- z = o + fc2_b; LN1; scatter store
  {
    float s1[4] = {0.f, 0.f, 0.f, 0.f}, q1[4] = {0.f, 0.f, 0.f, 0.f};
#pragma unroll
    for (int ni = 0; ni < 8; ++ni) {
      float fb = fc2_b[ni * 16 + c16];
#pragma unroll
      for (int r = 0; r < 4; ++r) {
        float v = o[ni][r] + fb;
        o[ni][r] = v;
        s1[r] += v; q1[r] += v * v;
      }
    }
#pragma unroll
    for (int r = 0; r < 4; ++r) {
      float s = qsum(s1[r]), q = qsum(q1[r]);
      float mean = s * 0.0078125f;
      float rstd = rsqrtf(q * 0.0078125f - mean * mean + 1e-5f);
#pragma unroll
      for (int ni = 0; ni < 8; ++ni) {
        int col = ni * 16 + c16;
        out[grow[r] + col] = (o[ni][r] - mean) * rstd * n1w[col] + n1b[col];
      }
    }
  }
}

extern "C" void kernel_launch(void* const* d_in, const int* in_sizes, int n_in,
                              void* d_out, int out_size, void* d_ws, size_t ws_size,
                              hipStream_t stream) {
  const float* x_v   = (const float*)d_in[0];
  const float* qkv_w = (const float*)d_in[1];
  const float* qkv_b = (const float*)d_in[2];
  const float* proj_w = (const float*)d_in[3];
  const float* proj_b = (const float*)d_in[4];
  const float* rpb_t = (const float*)d_in[5];
  const float* n1w = (const float*)d_in[6];
  const float* n1b = (const float*)d_in[7];
  const float* n2w = (const float*)d_in[8];
  const float* n2b = (const float*)d_in[9];
  const float* fc1_w = (const float*)d_in[10];
  const float* fc1_b = (const float*)d_in[11];
  const float* fc2_w = (const float*)d_in[12];
  const float* fc2_b = (const float*)d_in[13];

  char* ws = (char*)d_ws;
  us* qkvw    = (us*)(ws + 0);         //  98304
  us* projw   = (us*)(ws + 98304);     //  32768
  us* fc1w    = (us*)(ws + 131072);    // 131072
  us* fc2w    = (us*)(ws + 262144);    // 131072
  us* rpbm    = (us*)(ws + 393216);    // 131072
  us* attn_ws = (us*)(ws + 524288);    // 33554432

  prep_kernel<<<1024, 256, 0, stream>>>(qkv_w, proj_w, fc1_w, fc2_w, rpb_t,
                                        qkvw, projw, fc1w, fc2w, rpbm);
  qkv_attn_kernel<<<1024, 1024, 0, stream>>>(x_v, qkvw, qkv_b, rpbm, attn_ws);
  fused_kernel5<<<2048, 256, 0, stream>>>(attn_ws, projw, proj_b, x_v,
                                          fc1w, fc2w, fc1_b, fc2_b,
                                          n2w, n2b, n1w, n1b, (float*)d_out);
}

// Round 5
// 286.621 us; speedup vs baseline: 1.5971x; 1.5971x over previous
//
#include <hip/hip_runtime.h>

typedef unsigned short us;
typedef short s16x8 __attribute__((ext_vector_type(8)));
typedef float f32x4 __attribute__((ext_vector_type(4)));

__device__ __forceinline__ us f2bf(float f) {
  union { float f; unsigned u; } v; v.f = f;
  unsigned u = v.u;
  u += 0x7fffu + ((u >> 16) & 1u);   // RNE
  return (us)(u >> 16);
}
__device__ __forceinline__ float bf2f(us u) {
  union { unsigned u; float f; } v; v.u = ((unsigned)u) << 16; return v.f;
}
__device__ __forceinline__ s16x8 ld8(const us* p) { return *(const s16x8*)p; }

#define MFMA(a, b, c) __builtin_amdgcn_mfma_f32_16x16x32_bf16(a, b, c, 0, 0, 0)

// wave-local LDS fence: drain this wave's LDS ops; no cross-wave barrier.
__device__ __forceinline__ void lds_fence() {
  asm volatile("s_waitcnt lgkmcnt(0)" ::: "memory");
}

__device__ __forceinline__ float qsum(float v) {
  v += __shfl_xor(v, 1, 64); v += __shfl_xor(v, 2, 64);
  v += __shfl_xor(v, 4, 64); v += __shfl_xor(v, 8, 64);
  return v;
}

// fast exact-erf GELU: A&S 7.1.26, |err(erf)| <= 1.5e-7
__device__ __forceinline__ float gelu_fast(float x) {
  float ax = fabsf(x);
  float t = __builtin_amdgcn_rcpf(1.f + 0.3275911f * ax);
  float p = t * (0.254829592f +
            t * (-0.284496736f +
            t * (1.421413741f +
            t * (-1.453152027f +
            t * 1.061405429f))));
  float e = __expf(-ax * ax);
  float er = copysignf(1.f - p * e, x);
  return 0.5f * x * (1.f + er);
}

// ---------- prep: weight swizzles + combined rpb+mask tables.
// B-swizzle: dst[((k>>3)*N + n)*8 + (k&7)] = bf16(W[n][k]) -> B-frag = one 16B load.
// fc1 is chunk-major (64-hidden chunks contiguous) so kernels can bulk-copy a
// chunk into LDS: addr = ((n>>6)*16 + (k>>3))*512 + (n&63)*8 + (k&7).
// rpbm[h][cls][n1][n2] = bf16(rpb + mask), cls = (wh==15)*2 + (ww==15).
__global__ void prep_kernel(const float* __restrict__ qkv_w, const float* __restrict__ proj_w,
                            const float* __restrict__ fc1_w, const float* __restrict__ fc2_w,
                            const float* __restrict__ rpb_table,
                            us* __restrict__ qkvw, us* __restrict__ projw,
                            us* __restrict__ fc1w, us* __restrict__ fc2w,
                            us* __restrict__ rpbm) {
  int id = blockIdx.x * 256 + threadIdx.x;
  if (id < 49152) {  // qkv (384,128); fold q-scale into Q cols (n<128)
    int n = id % 384, k = id / 384;
    float v = qkv_w[n * 128 + k];
    if (n < 128) v *= 0.17677669529663687f;
    qkvw[(((k >> 3) * 384 + n) << 3) + (k & 7)] = f2bf(v);
    return;
  }
  id -= 49152;
  if (id < 16384) { int n = id % 128, k = id / 128;
    projw[(((k >> 3) * 128 + n) << 3) + (k & 7)] = f2bf(proj_w[n * 128 + k]); return; }
  id -= 16384;
  if (id < 65536) { int n = id % 512, k = id / 512;
    fc1w[((n >> 6) * 16 + (k >> 3)) * 512 + (n & 63) * 8 + (k & 7)] = f2bf(fc1_w[n * 128 + k]);
    return; }
  id -= 65536;
  if (id < 65536) { int n = id % 128, k = id / 128;
    fc2w[(((k >> 3) * 128 + n) << 3) + (k & 7)] = f2bf(fc2_w[n * 512 + k]); return; }
  id -= 65536;
  {
    int h = id >> 14, cls = (id >> 12) & 3, e = id & 4095;
    int n1 = e >> 6, n2 = e & 63;
    int r1 = n1 >> 3, c1 = n1 & 7, r2 = n2 >> 3, c2 = n2 & 7;
    int cH = cls >> 1, cW = cls & 1;
    int cq = (cH ? (r1 < 4 ? 1 : 2) : 0) * 3 + (cW ? (c1 < 4 ? 1 : 2) : 0);
    int ck = (cH ? (r2 < 4 ? 1 : 2) : 0) * 3 + (cW ? (c2 < 4 ? 1 : 2) : 0);
    int ridx = (r1 - r2 + 7) * 15 + (c1 - c2 + 7);
    float v = rpb_table[ridx * 4 + h] + (cq != ck ? -100.f : 0.f);
    rpbm[id] = f2bf(v);
  }
}

// ---------- K1: fused per-window QKV GEMM + attention, 8 waves (512 thr). [R2]
__global__ __launch_bounds__(512, 2) void qkv_attn_kernel(
    const float* __restrict__ x_v, const us* __restrict__ qkvw,
    const float* __restrict__ qkv_b, const us* __restrict__ rpbm,
    us* __restrict__ attn_out) {
  __shared__ __align__(16) unsigned char smem[139264];
  us* A   = (us*)smem;               // [128][136] bf16 rolled-x staging
  us* Qs  = (us*)smem;               // [128][136] tok-major (aliases A)
  us* Ks  = (us*)(smem + 34816);     // [128][136] tok-major
  us* Vts = (us*)(smem + 69632);     // [128][136] d-major (V transposed)
  // Pw per wave at 104448 + wv*4352   // [16][136]

  int w = blockIdx.x;
  int b = w >> 8, wi = w & 255, wh = wi >> 4, ww = wi & 15;
  int tid = threadIdx.x;

  { // gather: rolled(p) = orig((p+4)&127); 512 threads, 32 floats each
    int token = tid >> 2, q = tid & 3;
    int t = token >> 6, n = token & 63, r = n >> 3, c = n & 7;
    int hs = (wh * 8 + r + 4) & 127, wsc = (ww * 8 + c + 4) & 127;
    const float* src = x_v + (size_t)((b * 2 + t) * 16384 + hs * 128 + wsc) * 128 + q * 32;
    us* dst = A + token * 136 + q * 32;
#pragma unroll
    for (int i = 0; i < 4; ++i) {
      float4 f0 = ((const float4*)src)[2 * i];
      float4 f1 = ((const float4*)src)[2 * i + 1];
      s16x8 v;
      v[0] = (short)f2bf(f0.x); v[1] = (short)f2bf(f0.y);
      v[2] = (short)f2bf(f0.z); v[3] = (short)f2bf(f0.w);
      v[4] = (short)f2bf(f1.x); v[5] = (short)f2bf(f1.y);
      v[6] = (short)f2bf(f1.z); v[7] = (short)f2bf(f1.w);
      *(s16x8*)(dst + i * 8) = v;
    }
  }
  __syncthreads();

  int lane = tid & 63, wv = tid >> 6, quad = lane >> 4, c16 = lane & 15;
  int h = wv >> 1, p = wv & 1;
  int clsid = ((wh == 15) ? 2 : 0) + ((ww == 15) ? 1 : 0);

  // ---- QKV GEMM: wave (2h+p) -> head h, rows p*64..p*64+63.
  int rb = p * 64;
  f32x4 acc[4][6];
#pragma unroll
  for (int mi = 0; mi < 4; ++mi)
#pragma unroll
    for (int ni = 0; ni < 6; ++ni) acc[mi][ni] = (f32x4){0.f, 0.f, 0.f, 0.f};
#pragma unroll
  for (int ks = 0; ks < 4; ++ks) {
    int k0 = ks * 32;
    s16x8 af[4];
#pragma unroll
    for (int mi = 0; mi < 4; ++mi)
      af[mi] = ld8(A + (rb + mi * 16 + c16) * 136 + k0 + quad * 8);
#pragma unroll
    for (int ni = 0; ni < 6; ++ni) {
      int gcol = (ni >> 1) * 128 + h * 32 + (ni & 1) * 16 + c16;
      s16x8 bf = ld8(qkvw + ((((k0 >> 3) + quad) * 384 + gcol) << 3));
#pragma unroll
      for (int mi = 0; mi < 4; ++mi) acc[mi][ni] = MFMA(af[mi], bf, acc[mi][ni]);
    }
  }
  // all waves done READING A before Q writes overwrite the aliased bytes
  __syncthreads();
#pragma unroll
  for (int ni = 0; ni < 6; ++ni) {
    int part = ni >> 1, colh = (ni & 1) * 16 + c16;
    int col = h * 32 + colh;
    float bias = qkv_b[part * 128 + col];
    if (part == 0) bias *= 0.17677669529663687f;
#pragma unroll
    for (int mi = 0; mi < 4; ++mi)
#pragma unroll
      for (int r = 0; r < 4; ++r) {
        int tok = rb + mi * 16 + quad * 4 + r;
        us v = f2bf(acc[mi][ni][r] + bias);
        if (part == 0) Qs[tok * 136 + col] = v;          // tok-major
        else if (part == 1) Ks[tok * 136 + col] = v;     // tok-major
        else Vts[col * 136 + tok] = v;                   // d-major
      }
  }
  __syncthreads();  // sibling wave's Q/K/V visible

  // ---- attention: head h, q-tiles p*4 .. p*4+3; wave-local except K/V/Q reads.
  us* Pw = (us*)(smem + 104448 + wv * 4352);
  const us* rsrc = rpbm + ((h * 4 + clsid) << 12);
  int cb = h * 32;  // column base of this head

  for (int qq = 0; qq < 4; ++qq) {
    int q0 = (p * 4 + qq) * 16;
    s16x8 aq = ld8(Qs + (q0 + c16) * 136 + cb + quad * 8);
    // rpb+mask: 32 scalar 2B loads (L2-hot table); overlap with the MFMAs below
    float rbv[8][4];
#pragma unroll
    for (int nj = 0; nj < 8; ++nj) {
      int nk = (nj * 16 + c16) & 63;
#pragma unroll
      for (int r = 0; r < 4; ++r) {
        int nq = (q0 + quad * 4 + r) & 63;
        rbv[nj][r] = bf2f(rsrc[nq * 64 + nk]);
      }
    }
    f32x4 sacc[8];
#pragma unroll
    for (int nj = 0; nj < 8; ++nj) {
      s16x8 bk = ld8(Ks + (nj * 16 + c16) * 136 + cb + quad * 8);
      f32x4 z = (f32x4){0.f, 0.f, 0.f, 0.f};
      sacc[nj] = MFMA(aq, bk, z);
    }
    // softmax without max-subtraction (|scores| << 80, masked = -100 -> exp ~ 0)
    float sm[4] = {0.f, 0.f, 0.f, 0.f};
#pragma unroll
    for (int nj = 0; nj < 8; ++nj)
#pragma unroll
      for (int r = 0; r < 4; ++r) {
        float pp = __expf(sacc[nj][r] + rbv[nj][r]);
        sacc[nj][r] = pp;
        sm[r] += pp;
      }
    float inv[4];
#pragma unroll
    for (int r = 0; r < 4; ++r) inv[r] = 1.f / qsum(sm[r]);
    // P -> per-wave LDS (C-layout -> A-layout round trip)
#pragma unroll
    for (int nj = 0; nj < 8; ++nj)
#pragma unroll
      for (int r = 0; r < 4; ++r)
        Pw[(quad * 4 + r) * 136 + nj * 16 + c16] = f2bf(sacc[nj][r] * inv[r]);
    lds_fence();
    // PV
    f32x4 oacc[2];
    oacc[0] = (f32x4){0.f, 0.f, 0.f, 0.f};
    oacc[1] = (f32x4){0.f, 0.f, 0.f, 0.f};
#pragma unroll
    for (int ks = 0; ks < 4; ++ks) {
      int k0 = ks * 32;
      s16x8 ap = ld8(Pw + c16 * 136 + k0 + quad * 8);
#pragma unroll
      for (int nt = 0; nt < 2; ++nt) {
        s16x8 bv = ld8(Vts + (cb + nt * 16 + c16) * 136 + k0 + quad * 8);
        oacc[nt] = MFMA(ap, bv, oacc[nt]);
      }
    }
#pragma unroll
    for (int nt = 0; nt < 2; ++nt)
#pragma unroll
      for (int r = 0; r < 4; ++r) {
        int tok = q0 + quad * 4 + r;
        attn_out[((size_t)w * 128 + tok) * 128 + cb + nt * 16 + c16] =
            f2bf(oacc[nt][r]);
      }
    lds_fence();  // Pw WAR before next qc
  }
}

// ---------- K3: fused proj+LN2+MLP+LN1; 64 tokens/block (2048 blocks), wave owns
// 16 rows. R2 accumulator structure (96 VGPR, no seeding tricks — R3 lesson).
// NEW: fc1/fc2 chunk weights staged cooperatively into LDS (single 33KB buffer,
// padded rows for bank stagger). Moves B-frag reads from L2 (~400cyc, VGPR-
// limited in-flight) to LDS, and cuts per-block L2 weight traffic 4x.
// LDS: A[64][136] @0 | Ws1 16x520us @17408 | Ws2 8x1032us @34048 | Hw @50560
// total 59776 B -> still 2 blocks/CU.
__global__ __launch_bounds__(256) void fused_kernel6(
    const us* __restrict__ attn_ws, const us* __restrict__ projw,
    const float* __restrict__ proj_b, const float* __restrict__ x_v,
    const us* __restrict__ fc1w, const us* __restrict__ fc2w,
    const float* __restrict__ fc1_b, const float* __restrict__ fc2_b,
    const float* __restrict__ n2w, const float* __restrict__ n2b,
    const float* __restrict__ n1w, const float* __restrict__ n1b,
    float* __restrict__ out) {
  __shared__ __align__(16) unsigned char smem[59776];
  us* A   = (us*)smem;                 // [64][136]
  us* Ws1 = (us*)(smem + 17408);       // fc1 chunk: 16 rows x 520 us (pad 8)
  us* Ws2 = (us*)(smem + 34048);       // fc2 chunk: 8 rows x 1032 us (pad 8)
  int blk = blockIdx.x;
  int w = blk >> 1, hb = (blk & 1) * 64;
  int b = w >> 8, wi = w & 255, wh = wi >> 4, ww = wi & 15;
  int tid = threadIdx.x;
  int lane = tid & 63, wv = tid >> 6, quad = lane >> 4, c16 = lane & 15;
  int r0 = wv * 16;  // local row base within A
  us* Hw = (us*)(smem + 50560 + wv * 2304);  // per-wave [16][72] gelu chunk

  {  // wave stages its own 16 rows (lane -> row r0+(lane>>2), 32 cols)
    int lr = r0 + (lane >> 2), q = lane & 3;
    const us* src = attn_ws + ((size_t)w * 128 + hb + lr) * 128 + q * 32;
    us* dst = A + lr * 136 + q * 32;
#pragma unroll
    for (int i = 0; i < 4; ++i) *(s16x8*)(dst + i * 8) = ld8(src + i * 8);
  }

  // residual addresses + prefetch x_v (consumed after proj)
  size_t grow[4];
  float xv[4][8];
#pragma unroll
  for (int r = 0; r < 4; ++r) {
    int tt = hb + r0 + quad * 4 + r;
    int t = tt >> 6, n = tt & 63, rr = n >> 3, cc2 = n & 7;
    int hf = (wh * 8 + rr + 4) & 127, wf = (ww * 8 + cc2 + 4) & 127;
    grow[r] = (size_t)((b * 2 + t) * 16384 + hf * 128 + wf) * 128;
#pragma unroll
    for (int ni = 0; ni < 8; ++ni) xv[r][ni] = x_v[grow[r] + ni * 16 + c16];
  }

  // ---- stage chunk 0 weights (overlaps with proj+LN2; consumed after barrier)
  {
#pragma unroll
    for (int i = 0; i < 4; ++i) {        // fc1: 4 rows/wave, 1024B each
      int j = wv * 4 + i;
      s16x8 t = ld8(fc1w + j * 512 + lane * 8);
      *(s16x8*)(Ws1 + j * 520 + lane * 8) = t;
    }
#pragma unroll
    for (int i = 0; i < 2; ++i) {        // fc2: 2 rows/wave, 2048B each
      int j = wv * 2 + i;
      s16x8 t0 = ld8(fc2w + j * 1024 + lane * 8);
      s16x8 t1 = ld8(fc2w + j * 1024 + 512 + lane * 8);
      *(s16x8*)(Ws2 + j * 1032 + lane * 8) = t0;
      *(s16x8*)(Ws2 + j * 1032 + 512 + lane * 8) = t1;
    }
  }
  lds_fence();  // own-wave A staging visible (Ws visibility via later barrier)

  // ---- proj: 16 rows x 128 cols, K=128 (B-frags wave-private from L2/L1)
  f32x4 y[8];
#pragma unroll
  for (int ni = 0; ni < 8; ++ni) y[ni] = (f32x4){0.f, 0.f, 0.f, 0.f};
#pragma unroll
  for (int ks = 0; ks < 4; ++ks) {
    int k0 = ks * 32;
    s16x8 af = ld8(A + (r0 + c16) * 136 + k0 + quad * 8);
#pragma unroll
    for (int ni = 0; ni < 8; ++ni) {
      s16x8 bf = ld8(projw + ((((k0 >> 3) + quad) * 128 + ni * 16 + c16) << 3));
      y[ni] = MFMA(af, bf, y[ni]);
    }
  }

  // ---- y += proj_b + shortcut; LN2 (wave-local); LN2'd x -> A
  {
    float sum[4] = {0.f, 0.f, 0.f, 0.f}, sq[4] = {0.f, 0.f, 0.f, 0.f};
#pragma unroll
    for (int ni = 0; ni < 8; ++ni) {
      float pb = proj_b[ni * 16 + c16];
#pragma unroll
      for (int r = 0; r < 4; ++r) {
        float v = y[ni][r] + pb + xv[r][ni];
        y[ni][r] = v;
        sum[r] += v; sq[r] += v * v;
      }
    }
#pragma unroll
    for (int r = 0; r < 4; ++r) {
      float s = qsum(sum[r]), q = qsum(sq[r]);
      float mean = s * 0.0078125f;
      float rstd = rsqrtf(q * 0.0078125f - mean * mean + 1e-5f);
      int m = r0 + quad * 4 + r;
#pragma unroll
      for (int ni = 0; ni < 8; ++ni) {
        int col = ni * 16 + c16;
        A[m * 136 + col] = f2bf((y[ni][r] - mean) * rstd * n2w[col] + n2b[col]);
      }
    }
  }
  lds_fence();

  // ---- MLP: 8 chunks of 64 hidden; weights from LDS; fc1 -> gelu -> fc2
  f32x4 o[8];
#pragma unroll
  for (int ni = 0; ni < 8; ++ni) o[ni] = (f32x4){0.f, 0.f, 0.f, 0.f};

  for (int cc = 0; cc < 8; ++cc) {
    __syncthreads();  // Ws[cc] writes visible to all waves (drains vmcnt too)
    f32x4 f[4];
#pragma unroll
    for (int ni = 0; ni < 4; ++ni) f[ni] = (f32x4){0.f, 0.f, 0.f, 0.f};
#pragma unroll
    for (int ks = 0; ks < 4; ++ks) {
      int k0 = ks * 32;
      s16x8 af = ld8(A + (r0 + c16) * 136 + k0 + quad * 8);
#pragma unroll
      for (int ni = 0; ni < 4; ++ni) {
        s16x8 bf = ld8(Ws1 + (ks * 4 + quad) * 520 + (ni * 16 + c16) * 8);
        f[ni] = MFMA(af, bf, f[ni]);
      }
    }
#pragma unroll
    for (int ni = 0; ni < 4; ++ni) {
      float bb = fc1_b[cc * 64 + ni * 16 + c16];
#pragma unroll
      for (int r = 0; r < 4; ++r) {
        float u = f[ni][r] + bb;
        Hw[(quad * 4 + r) * 72 + ni * 16 + c16] = f2bf(gelu_fast(u));
      }
    }
    lds_fence();
#pragma unroll
    for (int ks2 = 0; ks2 < 2; ++ks2) {
      s16x8 ah = ld8(Hw + c16 * 72 + ks2 * 32 + quad * 8);
#pragma unroll
      for (int ni = 0; ni < 8; ++ni) {
        s16x8 bf = ld8(Ws2 + (ks2 * 4 + quad) * 1032 + (ni * 16 + c16) * 8);
        o[ni] = MFMA(ah, bf, o[ni]);
      }
    }
    if (cc < 7) {
      __syncthreads();  // all waves done reading Ws[cc] (and own Hw) -> WAR safe
      int cn = cc + 1;
#pragma unroll
      for (int i = 0; i < 4; ++i) {
        int j = wv * 4 + i;
        s16x8 t = ld8(fc1w + (cn * 16 + j) * 512 + lane * 8);
        *(s16x8*)(Ws1 + j * 520 + lane * 8) = t;
      }
#pragma unroll
      for (int i = 0; i < 2; ++i) {
        int j = wv * 2 + i;
        s16x8 t0 = ld8(fc2w + cn * 8192 + j * 1024 + lane * 8);
        s16x8 t1 = ld8(fc2w + cn * 8192 + j * 1024 + 512 + lane * 8);
        *(s16x8*)(Ws2 + j * 1032 + lane * 8) = t0;
        *(s16x8*)(Ws2 + j * 1032 + 512 + lane * 8) = t1;
      }
    } else {
      lds_fence();  // final Hw WAR not needed; keep wave-local drain
    }
  }

  // ---- z = fc2 + bias + y; LN1; scatter store
  {
    float s1[4] = {0.f, 0.f, 0.f, 0.f}, q1[4] = {0.f, 0.f, 0.f, 0.f};
#pragma unroll
    for (int ni = 0; ni < 8; ++ni) {
      float fb = fc2_b[ni * 16 + c16];
#pragma unroll
      for (int r = 0; r < 4; ++r) {
        float v = o[ni][r] + fb + y[ni][r];
        y[ni][r] = v;
        s1[r] += v; q1[r] += v * v;
      }
    }
#pragma unroll
    for (int r = 0; r < 4; ++r) {
      float s = qsum(s1[r]), q = qsum(q1[r]);
      float mean = s * 0.0078125f;
      float rstd = rsqrtf(q * 0.0078125f - mean * mean + 1e-5f);
#pragma unroll
      for (int ni = 0; ni < 8; ++ni) {
        int col = ni * 16 + c16;
        out[grow[r] + col] = (y[ni][r] - mean) * rstd * n1w[col] + n1b[col];
      }
    }
  }
}

extern "C" void kernel_launch(void* const* d_in, const int* in_sizes, int n_in,
                              void* d_out, int out_size, void* d_ws, size_t ws_size,
                              hipStream_t stream) {
  const float* x_v   = (const float*)d_in[0];
  const float* qkv_w = (const float*)d_in[1];
  const float* qkv_b = (const float*)d_in[2];
  const float* proj_w = (const float*)d_in[3];
  const float* proj_b = (const float*)d_in[4];
  const float* rpb_t = (const float*)d_in[5];
  const float* n1w = (const float*)d_in[6];
  const float* n1b = (const float*)d_in[7];
  const float* n2w = (const float*)d_in[8];
  const float* n2b = (const float*)d_in[9];
  const float* fc1_w = (const float*)d_in[10];
  const float* fc1_b = (const float*)d_in[11];
  const float* fc2_w = (const float*)d_in[12];
  const float* fc2_b = (const float*)d_in[13];

  char* ws = (char*)d_ws;
  us* qkvw    = (us*)(ws + 0);         //  98304
  us* projw   = (us*)(ws + 98304);     //  32768
  us* fc1w    = (us*)(ws + 131072);    // 131072
  us* fc2w    = (us*)(ws + 262144);    // 131072
  us* rpbm    = (us*)(ws + 393216);    // 131072
  us* attn_ws = (us*)(ws + 524288);    // 33554432

  prep_kernel<<<1024, 256, 0, stream>>>(qkv_w, proj_w, fc1_w, fc2_w, rpb_t,
                                        qkvw, projw, fc1w, fc2w, rpbm);
  qkv_attn_kernel<<<1024, 512, 0, stream>>>(x_v, qkvw, qkv_b, rpbm, attn_ws);
  fused_kernel6<<<2048, 256, 0, stream>>>(attn_ws, projw, proj_b, x_v,
                                          fc1w, fc2w, fc1_b, fc2_b,
                                          n2w, n2b, n1w, n1b, (float*)d_out);
}

// Round 6
// 273.436 us; speedup vs baseline: 1.6741x; 1.0482x over previous
//
#include <hip/hip_runtime.h>

typedef unsigned short us;
typedef short s16x8 __attribute__((ext_vector_type(8)));
typedef float f32x4 __attribute__((ext_vector_type(4)));

__device__ __forceinline__ us f2bf(float f) {
  union { float f; unsigned u; } v; v.f = f;
  unsigned u = v.u;
  u += 0x7fffu + ((u >> 16) & 1u);   // RNE
  return (us)(u >> 16);
}
__device__ __forceinline__ float bf2f(us u) {
  union { unsigned u; float f; } v; v.u = ((unsigned)u) << 16; return v.f;
}
__device__ __forceinline__ s16x8 ld8(const us* p) { return *(const s16x8*)p; }

#define MFMA(a, b, c) __builtin_amdgcn_mfma_f32_16x16x32_bf16(a, b, c, 0, 0, 0)

// wave-local LDS fence: drain this wave's LDS ops; no cross-wave barrier.
__device__ __forceinline__ void lds_fence() {
  asm volatile("s_waitcnt lgkmcnt(0)" ::: "memory");
}

__device__ __forceinline__ float qsum(float v) {
  v += __shfl_xor(v, 1, 64); v += __shfl_xor(v, 2, 64);
  v += __shfl_xor(v, 4, 64); v += __shfl_xor(v, 8, 64);
  return v;
}

// tanh-form GELU: 0.5x(1+tanh(0.79788456(x+0.044715x^3))) = x*sigmoid(z),
// z = x*(1.5957691 + 0.07135482 x^2). |err vs exact-erf gelu| <= ~3e-4.
__device__ __forceinline__ float gelu_fast(float x) {
  float x2 = x * x;
  float nz = x * (-1.5957691216f - 0.0713548163f * x2);  // -z
  float e = __expf(nz);
  return x * __builtin_amdgcn_rcpf(1.f + e);
}

// ---------- prep: weight swizzles + combined rpb+mask tables.
// qkv/proj B-swizzle: dst[((k>>3)*N + n)*8 + (k&7)] -> B-frag = one 16B load.
// fc1/fc2 are FRAGMENT-MAJOR per 64-hidden chunk: element for MFMA (ks,ni),
// lane l=(quad*16+c16), byte j sits at chunk*8192 + (ks*4+ni)*512 + l*8 + j.
// -> LDS stage = linear memcpy; LDS read = 64-lane contiguous 1KB (2-way bank, free).
// rpbm[h][cls][n1][n2] = bf16(rpb + mask), cls = (wh==15)*2 + (ww==15).
__global__ void prep_kernel(const float* __restrict__ qkv_w, const float* __restrict__ proj_w,
                            const float* __restrict__ fc1_w, const float* __restrict__ fc2_w,
                            const float* __restrict__ rpb_table,
                            us* __restrict__ qkvw, us* __restrict__ projw,
                            us* __restrict__ fc1w, us* __restrict__ fc2w,
                            us* __restrict__ rpbm) {
  int id = blockIdx.x * 256 + threadIdx.x;
  if (id < 49152) {  // qkv (384,128); fold q-scale into Q cols (n<128)
    int n = id % 384, k = id / 384;
    float v = qkv_w[n * 128 + k];
    if (n < 128) v *= 0.17677669529663687f;
    qkvw[(((k >> 3) * 384 + n) << 3) + (k & 7)] = f2bf(v);
    return;
  }
  id -= 49152;
  if (id < 16384) { int n = id % 128, k = id / 128;
    projw[(((k >> 3) * 128 + n) << 3) + (k & 7)] = f2bf(proj_w[n * 128 + k]); return; }
  id -= 16384;
  if (id < 65536) {  // fc1 (512,128) -> frag-major
    int n = id % 512, k = id / 512;
    int cc = n >> 6, ni = (n >> 4) & 3, c16v = n & 15;
    int ks = k >> 5, qd = (k >> 3) & 3, j = k & 7;
    fc1w[cc * 8192 + (ks * 4 + ni) * 512 + (qd * 16 + c16v) * 8 + j] = f2bf(fc1_w[n * 128 + k]);
    return; }
  id -= 65536;
  if (id < 65536) {  // fc2 (128,512) -> frag-major
    int n = id % 128, k = id / 128;
    int cc = k >> 6, ks2 = (k >> 5) & 1, qd = (k >> 3) & 3, j = k & 7;
    int ni = n >> 4, c16v = n & 15;
    fc2w[cc * 8192 + (ks2 * 8 + ni) * 512 + (qd * 16 + c16v) * 8 + j] = f2bf(fc2_w[n * 512 + k]);
    return; }
  id -= 65536;
  {
    int h = id >> 14, cls = (id >> 12) & 3, e = id & 4095;
    int n1 = e >> 6, n2 = e & 63;
    int r1 = n1 >> 3, c1 = n1 & 7, r2 = n2 >> 3, c2 = n2 & 7;
    int cH = cls >> 1, cW = cls & 1;
    int cq = (cH ? (r1 < 4 ? 1 : 2) : 0) * 3 + (cW ? (c1 < 4 ? 1 : 2) : 0);
    int ck = (cH ? (r2 < 4 ? 1 : 2) : 0) * 3 + (cW ? (c2 < 4 ? 1 : 2) : 0);
    int ridx = (r1 - r2 + 7) * 15 + (c1 - c2 + 7);
    float v = rpb_table[ridx * 4 + h] + (cq != ck ? -100.f : 0.f);
    rpbm[id] = f2bf(v);
  }
}

// ---------- K1: fused per-window QKV GEMM + attention, 8 waves (512 thr). [R2]
__global__ __launch_bounds__(512, 2) void qkv_attn_kernel(
    const float* __restrict__ x_v, const us* __restrict__ qkvw,
    const float* __restrict__ qkv_b, const us* __restrict__ rpbm,
    us* __restrict__ attn_out) {
  __shared__ __align__(16) unsigned char smem[139264];
  us* A   = (us*)smem;               // [128][136] bf16 rolled-x staging
  us* Qs  = (us*)smem;               // [128][136] tok-major (aliases A)
  us* Ks  = (us*)(smem + 34816);     // [128][136] tok-major
  us* Vts = (us*)(smem + 69632);     // [128][136] d-major (V transposed)
  // Pw per wave at 104448 + wv*4352   // [16][136]

  int w = blockIdx.x;
  int b = w >> 8, wi = w & 255, wh = wi >> 4, ww = wi & 15;
  int tid = threadIdx.x;

  { // gather: rolled(p) = orig((p+4)&127); 512 threads, 32 floats each
    int token = tid >> 2, q = tid & 3;
    int t = token >> 6, n = token & 63, r = n >> 3, c = n & 7;
    int hs = (wh * 8 + r + 4) & 127, wsc = (ww * 8 + c + 4) & 127;
    const float* src = x_v + (size_t)((b * 2 + t) * 16384 + hs * 128 + wsc) * 128 + q * 32;
    us* dst = A + token * 136 + q * 32;
#pragma unroll
    for (int i = 0; i < 4; ++i) {
      float4 f0 = ((const float4*)src)[2 * i];
      float4 f1 = ((const float4*)src)[2 * i + 1];
      s16x8 v;
      v[0] = (short)f2bf(f0.x); v[1] = (short)f2bf(f0.y);
      v[2] = (short)f2bf(f0.z); v[3] = (short)f2bf(f0.w);
      v[4] = (short)f2bf(f1.x); v[5] = (short)f2bf(f1.y);
      v[6] = (short)f2bf(f1.z); v[7] = (short)f2bf(f1.w);
      *(s16x8*)(dst + i * 8) = v;
    }
  }
  __syncthreads();

  int lane = tid & 63, wv = tid >> 6, quad = lane >> 4, c16 = lane & 15;
  int h = wv >> 1, p = wv & 1;
  int clsid = ((wh == 15) ? 2 : 0) + ((ww == 15) ? 1 : 0);

  // ---- QKV GEMM: wave (2h+p) -> head h, rows p*64..p*64+63.
  int rb = p * 64;
  f32x4 acc[4][6];
#pragma unroll
  for (int mi = 0; mi < 4; ++mi)
#pragma unroll
    for (int ni = 0; ni < 6; ++ni) acc[mi][ni] = (f32x4){0.f, 0.f, 0.f, 0.f};
#pragma unroll
  for (int ks = 0; ks < 4; ++ks) {
    int k0 = ks * 32;
    s16x8 af[4];
#pragma unroll
    for (int mi = 0; mi < 4; ++mi)
      af[mi] = ld8(A + (rb + mi * 16 + c16) * 136 + k0 + quad * 8);
#pragma unroll
    for (int ni = 0; ni < 6; ++ni) {
      int gcol = (ni >> 1) * 128 + h * 32 + (ni & 1) * 16 + c16;
      s16x8 bf = ld8(qkvw + ((((k0 >> 3) + quad) * 384 + gcol) << 3));
#pragma unroll
      for (int mi = 0; mi < 4; ++mi) acc[mi][ni] = MFMA(af[mi], bf, acc[mi][ni]);
    }
  }
  // all waves done READING A before Q writes overwrite the aliased bytes
  __syncthreads();
#pragma unroll
  for (int ni = 0; ni < 6; ++ni) {
    int part = ni >> 1, colh = (ni & 1) * 16 + c16;
    int col = h * 32 + colh;
    float bias = qkv_b[part * 128 + col];
    if (part == 0) bias *= 0.17677669529663687f;
#pragma unroll
    for (int mi = 0; mi < 4; ++mi)
#pragma unroll
      for (int r = 0; r < 4; ++r) {
        int tok = rb + mi * 16 + quad * 4 + r;
        us v = f2bf(acc[mi][ni][r] + bias);
        if (part == 0) Qs[tok * 136 + col] = v;          // tok-major
        else if (part == 1) Ks[tok * 136 + col] = v;     // tok-major
        else Vts[col * 136 + tok] = v;                   // d-major
      }
  }
  __syncthreads();  // sibling wave's Q/K/V visible

  // ---- attention: head h, q-tiles p*4 .. p*4+3; wave-local except K/V/Q reads.
  us* Pw = (us*)(smem + 104448 + wv * 4352);
  const us* rsrc = rpbm + ((h * 4 + clsid) << 12);
  int cb = h * 32;  // column base of this head

  for (int qq = 0; qq < 4; ++qq) {
    int q0 = (p * 4 + qq) * 16;
    s16x8 aq = ld8(Qs + (q0 + c16) * 136 + cb + quad * 8);
    // rpb+mask: 32 scalar 2B loads (L2-hot table); overlap with the MFMAs below
    float rbv[8][4];
#pragma unroll
    for (int nj = 0; nj < 8; ++nj) {
      int nk = (nj * 16 + c16) & 63;
#pragma unroll
      for (int r = 0; r < 4; ++r) {
        int nq = (q0 + quad * 4 + r) & 63;
        rbv[nj][r] = bf2f(rsrc[nq * 64 + nk]);
      }
    }
    f32x4 sacc[8];
#pragma unroll
    for (int nj = 0; nj < 8; ++nj) {
      s16x8 bk = ld8(Ks + (nj * 16 + c16) * 136 + cb + quad * 8);
      f32x4 z = (f32x4){0.f, 0.f, 0.f, 0.f};
      sacc[nj] = MFMA(aq, bk, z);
    }
    // softmax without max-subtraction (|scores| << 80, masked = -100 -> exp ~ 0)
    float sm[4] = {0.f, 0.f, 0.f, 0.f};
#pragma unroll
    for (int nj = 0; nj < 8; ++nj)
#pragma unroll
      for (int r = 0; r < 4; ++r) {
        float pp = __expf(sacc[nj][r] + rbv[nj][r]);
        sacc[nj][r] = pp;
        sm[r] += pp;
      }
    float inv[4];
#pragma unroll
    for (int r = 0; r < 4; ++r) inv[r] = 1.f / qsum(sm[r]);
    // P -> per-wave LDS (C-layout -> A-layout round trip)
#pragma unroll
    for (int nj = 0; nj < 8; ++nj)
#pragma unroll
      for (int r = 0; r < 4; ++r)
        Pw[(quad * 4 + r) * 136 + nj * 16 + c16] = f2bf(sacc[nj][r] * inv[r]);
    lds_fence();
    // PV
    f32x4 oacc[2];
    oacc[0] = (f32x4){0.f, 0.f, 0.f, 0.f};
    oacc[1] = (f32x4){0.f, 0.f, 0.f, 0.f};
#pragma unroll
    for (int ks = 0; ks < 4; ++ks) {
      int k0 = ks * 32;
      s16x8 ap = ld8(Pw + c16 * 136 + k0 + quad * 8);
#pragma unroll
      for (int nt = 0; nt < 2; ++nt) {
        s16x8 bv = ld8(Vts + (cb + nt * 16 + c16) * 136 + k0 + quad * 8);
        oacc[nt] = MFMA(ap, bv, oacc[nt]);
      }
    }
#pragma unroll
    for (int nt = 0; nt < 2; ++nt)
#pragma unroll
      for (int r = 0; r < 4; ++r) {
        int tok = q0 + quad * 4 + r;
        attn_out[((size_t)w * 128 + tok) * 128 + cb + nt * 16 + c16] =
            f2bf(oacc[nt][r]);
      }
    lds_fence();  // Pw WAR before next qc
  }
}

// ---------- K3: fused proj+LN2+MLP+LN1; 64 tokens/block (2048 blocks), wave owns
// 16 rows. R4 structure + three fixes:
//  (1) Ws1/Ws2 frag-major: LDS reads 64-lane contiguous 1KB (2-way, free);
//      staging = linear coalesced memcpy.  (2) MLP A-frags hoisted to regs
//      (were re-read 8x from conflicted LDS).  (3) tanh-GELU (8 VALU vs ~20).
// LDS: A[64][136] @0 | Ws1 8192us @17408 | Ws2 8192us @33792 | Hw @50176
// total 59392 B -> 2 blocks/CU.
__global__ __launch_bounds__(256) void fused_kernel7(
    const us* __restrict__ attn_ws, const us* __restrict__ projw,
    const float* __restrict__ proj_b, const float* __restrict__ x_v,
    const us* __restrict__ fc1w, const us* __restrict__ fc2w,
    const float* __restrict__ fc1_b, const float* __restrict__ fc2_b,
    const float* __restrict__ n2w, const float* __restrict__ n2b,
    const float* __restrict__ n1w, const float* __restrict__ n1b,
    float* __restrict__ out) {
  __shared__ __align__(16) unsigned char smem[59392];
  us* A   = (us*)smem;                 // [64][136]
  us* Ws1 = (us*)(smem + 17408);       // fc1 chunk, frag-major 8192 us
  us* Ws2 = (us*)(smem + 33792);       // fc2 chunk, frag-major 8192 us
  int blk = blockIdx.x;
  int w = blk >> 1, hb = (blk & 1) * 64;
  int b = w >> 8, wi = w & 255, wh = wi >> 4, ww = wi & 15;
  int tid = threadIdx.x;
  int lane = tid & 63, wv = tid >> 6, quad = lane >> 4, c16 = lane & 15;
  int r0 = wv * 16;  // local row base within A
  us* Hw = (us*)(smem + 50176 + wv * 2304);  // per-wave [16][72] gelu chunk

  {  // wave stages its own 16 rows (lane -> row r0+(lane>>2), 32 cols)
    int lr = r0 + (lane >> 2), q = lane & 3;
    const us* src = attn_ws + ((size_t)w * 128 + hb + lr) * 128 + q * 32;
    us* dst = A + lr * 136 + q * 32;
#pragma unroll
    for (int i = 0; i < 4; ++i) *(s16x8*)(dst + i * 8) = ld8(src + i * 8);
  }

  // residual addresses + prefetch x_v (consumed after proj)
  size_t grow[4];
  float xv[4][8];
#pragma unroll
  for (int r = 0; r < 4; ++r) {
    int tt = hb + r0 + quad * 4 + r;
    int t = tt >> 6, n = tt & 63, rr = n >> 3, cc2 = n & 7;
    int hf = (wh * 8 + rr + 4) & 127, wf = (ww * 8 + cc2 + 4) & 127;
    grow[r] = (size_t)((b * 2 + t) * 16384 + hf * 128 + wf) * 128;
#pragma unroll
    for (int ni = 0; ni < 8; ++ni) xv[r][ni] = x_v[grow[r] + ni * 16 + c16];
  }

  // ---- stage chunk 0 weights (linear copy; overlaps with proj+LN2)
  {
    const s16x8* s1 = (const s16x8*)fc1w;
    const s16x8* s2 = (const s16x8*)fc2w;
    s16x8* d1 = (s16x8*)Ws1;
    s16x8* d2 = (s16x8*)Ws2;
#pragma unroll
    for (int i = 0; i < 4; ++i) d1[i * 256 + tid] = s1[i * 256 + tid];
#pragma unroll
    for (int i = 0; i < 4; ++i) d2[i * 256 + tid] = s2[i * 256 + tid];
  }
  lds_fence();  // own-wave A staging visible (Ws visibility via later barrier)

  // ---- proj: 16 rows x 128 cols, K=128 (B-frags wave-private from L2/L1)
  f32x4 y[8];
#pragma unroll
  for (int ni = 0; ni < 8; ++ni) y[ni] = (f32x4){0.f, 0.f, 0.f, 0.f};
#pragma unroll
  for (int ks = 0; ks < 4; ++ks) {
    int k0 = ks * 32;
    s16x8 af = ld8(A + (r0 + c16) * 136 + k0 + quad * 8);
#pragma unroll
    for (int ni = 0; ni < 8; ++ni) {
      s16x8 bf = ld8(projw + ((((k0 >> 3) + quad) * 128 + ni * 16 + c16) << 3));
      y[ni] = MFMA(af, bf, y[ni]);
    }
  }

  // ---- y += proj_b + shortcut; LN2 (wave-local); LN2'd x -> A
  {
    float sum[4] = {0.f, 0.f, 0.f, 0.f}, sq[4] = {0.f, 0.f, 0.f, 0.f};
#pragma unroll
    for (int ni = 0; ni < 8; ++ni) {
      float pb = proj_b[ni * 16 + c16];
#pragma unroll
      for (int r = 0; r < 4; ++r) {
        float v = y[ni][r] + pb + xv[r][ni];
        y[ni][r] = v;
        sum[r] += v; sq[r] += v * v;
      }
    }
#pragma unroll
    for (int r = 0; r < 4; ++r) {
      float s = qsum(sum[r]), q = qsum(sq[r]);
      float mean = s * 0.0078125f;
      float rstd = rsqrtf(q * 0.0078125f - mean * mean + 1e-5f);
      int m = r0 + quad * 4 + r;
#pragma unroll
      for (int ni = 0; ni < 8; ++ni) {
        int col = ni * 16 + c16;
        A[m * 136 + col] = f2bf((y[ni][r] - mean) * rstd * n2w[col] + n2b[col]);
      }
    }
  }
  lds_fence();

  // ---- hoist MLP A-frags (LN2'd x): same 4 frags reused by all 8 chunks
  s16x8 afm[4];
#pragma unroll
  for (int ks = 0; ks < 4; ++ks)
    afm[ks] = ld8(A + (r0 + c16) * 136 + ks * 32 + quad * 8);

  // ---- MLP: 8 chunks of 64 hidden; weights from LDS (frag-major)
  f32x4 o[8];
#pragma unroll
  for (int ni = 0; ni < 8; ++ni) o[ni] = (f32x4){0.f, 0.f, 0.f, 0.f};

  for (int cc = 0; cc < 8; ++cc) {
    __syncthreads();  // Ws[cc] writes visible to all waves (drains vmcnt too)
    f32x4 f[4];
#pragma unroll
    for (int ni = 0; ni < 4; ++ni) f[ni] = (f32x4){0.f, 0.f, 0.f, 0.f};
#pragma unroll
    for (int ks = 0; ks < 4; ++ks)
#pragma unroll
      for (int ni = 0; ni < 4; ++ni) {
        s16x8 bf = ld8(Ws1 + (ks * 4 + ni) * 512 + lane * 8);
        f[ni] = MFMA(afm[ks], bf, f[ni]);
      }
#pragma unroll
    for (int ni = 0; ni < 4; ++ni) {
      float bb = fc1_b[cc * 64 + ni * 16 + c16];
#pragma unroll
      for (int r = 0; r < 4; ++r) {
        float u = f[ni][r] + bb;
        Hw[(quad * 4 + r) * 72 + ni * 16 + c16] = f2bf(gelu_fast(u));
      }
    }
    lds_fence();
#pragma unroll
    for (int ks2 = 0; ks2 < 2; ++ks2) {
      s16x8 ah = ld8(Hw + c16 * 72 + ks2 * 32 + quad * 8);
#pragma unroll
      for (int ni = 0; ni < 8; ++ni) {
        s16x8 bf = ld8(Ws2 + (ks2 * 8 + ni) * 512 + lane * 8);
        o[ni] = MFMA(ah, bf, o[ni]);
      }
    }
    if (cc < 7) {
      __syncthreads();  // all waves done reading Ws[cc] (and own Hw) -> WAR safe
      int cn = cc + 1;
      const s16x8* s1 = (const s16x8*)fc1w + cn * 1024;
      const s16x8* s2 = (const s16x8*)fc2w + cn * 1024;
      s16x8* d1 = (s16x8*)Ws1;
      s16x8* d2 = (s16x8*)Ws2;
#pragma unroll
      for (int i = 0; i < 4; ++i) d1[i * 256 + tid] = s1[i * 256 + tid];
#pragma unroll
      for (int i = 0; i < 4; ++i) d2[i * 256 + tid] = s2[i * 256 + tid];
    } else {
      lds_fence();  // final wave-local drain
    }
  }

  // ---- z = fc2 + bias + y; LN1; scatter store
  {
    float s1v[4] = {0.f, 0.f, 0.f, 0.f}, q1[4] = {0.f, 0.f, 0.f, 0.f};
#pragma unroll
    for (int ni = 0; ni < 8; ++ni) {
      float fb = fc2_b[ni * 16 + c16];
#pragma unroll
      for (int r = 0; r < 4; ++r) {
        float v = o[ni][r] + fb + y[ni][r];
        y[ni][r] = v;
        s1v[r] += v; q1[r] += v * v;
      }
    }
#pragma unroll
    for (int r = 0; r < 4; ++r) {
      float s = qsum(s1v[r]), q = qsum(q1[r]);
      float mean = s * 0.0078125f;
      float rstd = rsqrtf(q * 0.0078125f - mean * mean + 1e-5f);
#pragma unroll
      for (int ni = 0; ni < 8; ++ni) {
        int col = ni * 16 + c16;
        out[grow[r] + col] = (y[ni][r] - mean) * rstd * n1w[col] + n1b[col];
      }
    }
  }
}

extern "C" void kernel_launch(void* const* d_in, const int* in_sizes, int n_in,
                              void* d_out, int out_size, void* d_ws, size_t ws_size,
                              hipStream_t stream) {
  const float* x_v   = (const float*)d_in[0];
  const float* qkv_w = (const float*)d_in[1];
  const float* qkv_b = (const float*)d_in[2];
  const float* proj_w = (const float*)d_in[3];
  const float* proj_b = (const float*)d_in[4];
  const float* rpb_t = (const float*)d_in[5];
  const float* n1w = (const float*)d_in[6];
  const float* n1b = (const float*)d_in[7];
  const float* n2w = (const float*)d_in[8];
  const float* n2b = (const float*)d_in[9];
  const float* fc1_w = (const float*)d_in[10];
  const float* fc1_b = (const float*)d_in[11];
  const float* fc2_w = (const float*)d_in[12];
  const float* fc2_b = (const float*)d_in[13];

  char* ws = (char*)d_ws;
  us* qkvw    = (us*)(ws + 0);         //  98304
  us* projw   = (us*)(ws + 98304);     //  32768
  us* fc1w    = (us*)(ws + 131072);    // 131072
  us* fc2w    = (us*)(ws + 262144);    // 131072
  us* rpbm    = (us*)(ws + 393216);    // 131072
  us* attn_ws = (us*)(ws + 524288);    // 33554432

  prep_kernel<<<1024, 256, 0, stream>>>(qkv_w, proj_w, fc1_w, fc2_w, rpb_t,
                                        qkvw, projw, fc1w, fc2w, rpbm);
  qkv_attn_kernel<<<1024, 512, 0, stream>>>(x_v, qkvw, qkv_b, rpbm, attn_ws);
  fused_kernel7<<<2048, 256, 0, stream>>>(attn_ws, projw, proj_b, x_v,
                                          fc1w, fc2w, fc1_b, fc2_b,
                                          n2w, n2b, n1w, n1b, (float*)d_out);
}